// Round 4
// baseline (116.714 us; speedup 1.0000x reference)
//
#include <hip/hip_runtime.h>
#include <math.h>

// x: (B,S,G,D) f32, norm_scale: (G,D) f32, conv_kernel: (K, G*D) f32
// out: (B,S,G,D) f32.  B=4, S=4096, G=4, D=1024, K=4, C=4096
constexpr int B = 4;
constexpr int S = 4096;
constexpr int G = 4;
constexpr int D = 1024;
constexpr int K = 4;
constexpr int C = G * D;
constexpr int CHUNK = 32;            // s-rows per block: 2048 blocks = 8/CU
constexpr float EPS = 1e-6f;

typedef float v4f __attribute__((ext_vector_type(4)));  // native vec for nt-store

// Fused RMSNorm + causal depthwise conv1d (K=4) + SiLU.
// Block = (b, g, s-chunk). 256 threads; thread t owns channels 4t..4t+3.
// 2 rows per iteration, one barrier per pair (parity double-buffered LDS),
// 2-row-deep load prefetch. Window of 3 normalized rows in registers.
__global__ __launch_bounds__(256)
void shortconv_fused_kernel(const float* __restrict__ x,
                            const float* __restrict__ scale,
                            const float* __restrict__ w,
                            float* __restrict__ out)
{
    __shared__ float red[2][2][4];   // [parity][row-in-pair][wave]

    const int tid  = threadIdx.x;
    const int lane = tid & 63;
    const int wid  = tid >> 6;
    const int bg   = blockIdx.y;     // 0..B*G-1
    const int b    = bg >> 2;        // G=4
    const int g    = bg & 3;
    const int s0   = blockIdx.x * CHUNK;
    const int d0   = tid * 4;

    const size_t srow = (size_t)G * D;
    const size_t base = (size_t)b * S * srow + (size_t)g * D + d0;

    const float4 sc = *(const float4*)(scale + g * D + d0);
    const float4 w0 = *(const float4*)(w + 0 * C + g * D + d0);
    const float4 w1 = *(const float4*)(w + 1 * C + g * D + d0);
    const float4 w2 = *(const float4*)(w + 2 * C + g * D + d0);
    const float4 w3 = *(const float4*)(w + 3 * C + g * D + d0);

    const float4 zero = make_float4(0.f, 0.f, 0.f, 0.f);

    // Window: normalized rows s-3, s-2, s-1 (s = first row of current pair).
    float4 win0 = zero, win1 = zero, win2 = zero;

    // Pipeline starts at s0-4 (even); first pair's outputs are discarded
    // (s < s0) but its rows feed the window. Negative rows read as zero.
    int s = s0 - 4;
    float4 cur0 = (s     >= 0) ? *(const float4*)(x + base + (size_t)(s    ) * srow) : zero;
    float4 cur1 = (s + 1 >= 0) ? *(const float4*)(x + base + (size_t)(s + 1) * srow) : zero;

    const int s_end = s0 + CHUNK;
    for (; s < s_end; s += 2) {
        // Prefetch the next pair (2 rows deep).
        float4 nxt0 = zero, nxt1 = zero;
        if (s + 2 < s_end) {
            if (s + 2 >= 0) nxt0 = *(const float4*)(x + base + (size_t)(s + 2) * srow);
            if (s + 3 >= 0) nxt1 = *(const float4*)(x + base + (size_t)(s + 3) * srow);
        }

        // Sum of squares for both rows (interleaved shuffle chains for ILP).
        float l0 = cur0.x * cur0.x + cur0.y * cur0.y + cur0.z * cur0.z + cur0.w * cur0.w;
        float l1 = cur1.x * cur1.x + cur1.y * cur1.y + cur1.z * cur1.z + cur1.w * cur1.w;
        #pragma unroll
        for (int off = 32; off > 0; off >>= 1) {
            l0 += __shfl_xor(l0, off, 64);
            l1 += __shfl_xor(l1, off, 64);
        }
        const int buf = (s >> 1) & 1;
        if (lane == 0) {
            red[buf][0][wid] = l0;
            red[buf][1][wid] = l1;
        }
        __syncthreads();
        const float t0 = red[buf][0][0] + red[buf][0][1] + red[buf][0][2] + red[buf][0][3];
        const float t1 = red[buf][1][0] + red[buf][1][1] + red[buf][1][2] + red[buf][1][3];
        const float invr0 = rsqrtf(t0 * (1.0f / D) + EPS);
        const float invr1 = rsqrtf(t1 * (1.0f / D) + EPS);

        float4 nv0, nv1;
        nv0.x = cur0.x * invr0 * sc.x;  nv0.y = cur0.y * invr0 * sc.y;
        nv0.z = cur0.z * invr0 * sc.z;  nv0.w = cur0.w * invr0 * sc.w;
        nv1.x = cur1.x * invr1 * sc.x;  nv1.y = cur1.y * invr1 * sc.y;
        nv1.z = cur1.z * invr1 * sc.z;  nv1.w = cur1.w * invr1 * sc.w;

        if (s >= s0) {
            // y[s]   = w0*xn[s-3] + w1*xn[s-2] + w2*xn[s-1] + w3*xn[s]
            // y[s+1] = w0*xn[s-2] + w1*xn[s-1] + w2*xn[s]   + w3*xn[s+1]
            float4 y0, y1;
            y0.x = w0.x * win0.x + w1.x * win1.x + w2.x * win2.x + w3.x * nv0.x;
            y0.y = w0.y * win0.y + w1.y * win1.y + w2.y * win2.y + w3.y * nv0.y;
            y0.z = w0.z * win0.z + w1.z * win1.z + w2.z * win2.z + w3.z * nv0.z;
            y0.w = w0.w * win0.w + w1.w * win1.w + w2.w * win2.w + w3.w * nv0.w;
            y1.x = w0.x * win1.x + w1.x * win2.x + w2.x * nv0.x + w3.x * nv1.x;
            y1.y = w0.y * win1.y + w1.y * win2.y + w2.y * nv0.y + w3.y * nv1.y;
            y1.z = w0.z * win1.z + w1.z * win2.z + w2.z * nv0.z + w3.z * nv1.z;
            y1.w = w0.w * win1.w + w1.w * win2.w + w2.w * nv0.w + w3.w * nv1.w;
            // SiLU via fast rcp: y * 1/(1+exp(-y))
            y0.x *= __builtin_amdgcn_rcpf(1.f + __expf(-y0.x));
            y0.y *= __builtin_amdgcn_rcpf(1.f + __expf(-y0.y));
            y0.z *= __builtin_amdgcn_rcpf(1.f + __expf(-y0.z));
            y0.w *= __builtin_amdgcn_rcpf(1.f + __expf(-y0.w));
            y1.x *= __builtin_amdgcn_rcpf(1.f + __expf(-y1.x));
            y1.y *= __builtin_amdgcn_rcpf(1.f + __expf(-y1.y));
            y1.z *= __builtin_amdgcn_rcpf(1.f + __expf(-y1.z));
            y1.w *= __builtin_amdgcn_rcpf(1.f + __expf(-y1.w));
            v4f yv0 = { y0.x, y0.y, y0.z, y0.w };
            v4f yv1 = { y1.x, y1.y, y1.z, y1.w };
            __builtin_nontemporal_store(yv0, (v4f*)(out + base + (size_t)(s    ) * srow));
            __builtin_nontemporal_store(yv1, (v4f*)(out + base + (size_t)(s + 1) * srow));
        }

        // Shift window by 2 rows.
        win0 = win2;
        win1 = nv0;
        win2 = nv1;
        cur0 = nxt0;
        cur1 = nxt1;
    }
}

extern "C" void kernel_launch(void* const* d_in, const int* in_sizes, int n_in,
                              void* d_out, int out_size, void* d_ws, size_t ws_size,
                              hipStream_t stream) {
    const float* x     = (const float*)d_in[0];
    const float* scale = (const float*)d_in[1];
    const float* w     = (const float*)d_in[2];
    float* out         = (float*)d_out;

    dim3 grid(S / CHUNK, B * G);
    dim3 block(256);
    shortconv_fused_kernel<<<grid, block, 0, stream>>>(x, scale, w, out);
}

// Round 5
// 88.829 us; speedup vs baseline: 1.3139x; 1.3139x over previous
//
#include <hip/hip_runtime.h>
#include <math.h>

// x: (B,S,G,D) f32, norm_scale: (G,D) f32, conv_kernel: (K, G*D) f32
// out: (B,S,G,D) f32.  B=4, S=4096, G=4, D=1024, K=4, C=4096
constexpr int B = 4;
constexpr int S = 4096;
constexpr int G = 4;
constexpr int D = 1024;
constexpr int K = 4;
constexpr int C = G * D;
constexpr int STRIP = 32;            // s-rows per wave
constexpr float EPS = 1e-6f;

typedef float v4f __attribute__((ext_vector_type(4)));

// Wave-autonomous fused RMSNorm + causal depthwise conv1d (K=4) + SiLU.
// One wave owns a full (b,g,s-strip): 64 lanes x 16 channels = D = 1024, so
// the RMS reduce is wave-internal (shfl only). NO __syncthreads, NO LDS.
// 2048 independent waves; per-wave 3-row register window + 1-row prefetch.
__global__ __launch_bounds__(256)
void shortconv_wave_kernel(const float* __restrict__ x,
                           const float* __restrict__ scale,
                           const float* __restrict__ w,
                           float* __restrict__ out)
{
    const int tid   = threadIdx.x;
    const int lane  = tid & 63;
    const int wid   = tid >> 6;
    const int gw    = blockIdx.x * 4 + wid;   // global wave id, 0..2047
    const int nstr  = S / STRIP;              // 128 strips per (b,g)
    const int strip = gw & (nstr - 1);
    const int bg    = gw >> 7;                // gw / nstr, 0..15
    const int b     = bg >> 2;
    const int g     = bg & 3;
    const int s0    = strip * STRIP;
    const int send  = s0 + STRIP;

    // lane owns channels g*D + lane*4 + j*256, j=0..3 (each load coalesced 1KB)
    const size_t base = (size_t)b * S * C + (size_t)g * D + (size_t)(lane * 4);
    const int    coff = g * D + lane * 4;

    v4f sc[4], wt0[4], wt1[4], wt2[4], wt3[4];
    #pragma unroll
    for (int j = 0; j < 4; ++j) {
        sc[j]  = *(const v4f*)(scale + coff + j * 256);
        wt0[j] = *(const v4f*)(w + 0 * C + coff + j * 256);
        wt1[j] = *(const v4f*)(w + 1 * C + coff + j * 256);
        wt2[j] = *(const v4f*)(w + 2 * C + coff + j * 256);
        wt3[j] = *(const v4f*)(w + 3 * C + coff + j * 256);
    }

    v4f win0[4], win1[4], win2[4], cur[4], nxt[4];
    #pragma unroll
    for (int j = 0; j < 4; ++j) {
        win0[j] = (v4f)0.f; win1[j] = (v4f)0.f; win2[j] = (v4f)0.f;
        nxt[j] = (v4f)0.f;
    }

    {   // load first pipeline row (s0-3); zero if before sequence start
        const int s = s0 - 3;
        #pragma unroll
        for (int j = 0; j < 4; ++j)
            cur[j] = (s >= 0) ? *(const v4f*)(x + base + (size_t)s * C + j * 256)
                              : (v4f)0.f;
    }

    for (int s = s0 - 3; s < send; ++s) {
        // Prefetch next row; overlaps with this row's reduce/compute.
        const int sn = s + 1;
        if (sn < send) {
            #pragma unroll
            for (int j = 0; j < 4; ++j)
                nxt[j] = (sn >= 0) ? *(const v4f*)(x + base + (size_t)sn * C + j * 256)
                                   : (v4f)0.f;
        }

        // Wave-local sum of squares over D=1024 (16 per lane + 6-step butterfly).
        v4f a = cur[0] * cur[0];
        a += cur[1] * cur[1];
        a += cur[2] * cur[2];
        a += cur[3] * cur[3];
        float local = a.x + a.y + a.z + a.w;
        #pragma unroll
        for (int off = 32; off > 0; off >>= 1)
            local += __shfl_xor(local, off, 64);
        const float invr = rsqrtf(local * (1.0f / D) + EPS);

        v4f nv[4];
        #pragma unroll
        for (int j = 0; j < 4; ++j)
            nv[j] = cur[j] * (invr * sc[j]);

        if (s >= s0) {
            #pragma unroll
            for (int j = 0; j < 4; ++j) {
                v4f y = wt0[j] * win0[j] + wt1[j] * win1[j]
                      + wt2[j] * win2[j] + wt3[j] * nv[j];
                y.x *= __builtin_amdgcn_rcpf(1.f + __expf(-y.x));
                y.y *= __builtin_amdgcn_rcpf(1.f + __expf(-y.y));
                y.z *= __builtin_amdgcn_rcpf(1.f + __expf(-y.z));
                y.w *= __builtin_amdgcn_rcpf(1.f + __expf(-y.w));
                __builtin_nontemporal_store(y, (v4f*)(out + base + (size_t)s * C + j * 256));
            }
        }

        #pragma unroll
        for (int j = 0; j < 4; ++j) {
            win0[j] = win1[j];
            win1[j] = win2[j];
            win2[j] = nv[j];
            cur[j]  = nxt[j];
        }
    }
}

extern "C" void kernel_launch(void* const* d_in, const int* in_sizes, int n_in,
                              void* d_out, int out_size, void* d_ws, size_t ws_size,
                              hipStream_t stream) {
    const float* x     = (const float*)d_in[0];
    const float* scale = (const float*)d_in[1];
    const float* w     = (const float*)d_in[2];
    float* out         = (float*)d_out;

    const int total_waves = (S / STRIP) * B * G;   // 2048
    dim3 grid(total_waves / 4);                    // 512 blocks of 4 waves
    dim3 block(256);
    shortconv_wave_kernel<<<grid, block, 0, stream>>>(x, scale, w, out);
}